// Round 8
// baseline (228.129 us; speedup 1.0000x reference)
//
#include <hip/hip_runtime.h>
#include <hip/hip_bf16.h>

// fp32 I/O, fp16 MFMA compute (verified: absmax 3.9e-3 vs thr 3.1e-2).
// R8: attn waves compute M=32 rows (K/V frag regs reused by 2 A-frags ->
//     halves LDS bytes per MFMA; attn was LDS-BW-bound), fixed CU pairing
//     (qt pairs sum to 15 -> 36 iters/CU), GEMM BK=64.

typedef __attribute__((ext_vector_type(8))) _Float16 vhalf8;
typedef __attribute__((ext_vector_type(4))) _Float16 vhalf4;
typedef __attribute__((ext_vector_type(4))) float vfloat4;

#define D_MODEL 1024
#define SEQ     2048
#define NB      2
#define NH      16
#define HD      64

// softmax: exp(s/8) = exp2(s * 0.125*log2(e)); constant offset cancels in o/l.
#define SCALE_K1 0.18033688f

__device__ __forceinline__ void async16(const void* g, void* l) {
  __builtin_amdgcn_global_load_lds(
      (const __attribute__((address_space(1))) unsigned int*)g,
      (__attribute__((address_space(3))) unsigned int*)l, 16, 0, 0);
}

// ---------------------------------------------------------------------------
// prep: z<4 -> weight transpose+convert planes; z==4 -> x fp32->fp16 convert.
// ---------------------------------------------------------------------------
__global__ __launch_bounds__(256) void prep(
    const float* __restrict__ x,
    const float* __restrict__ Wq, const float* __restrict__ Wk,
    const float* __restrict__ Wv, const float* __restrict__ Wo,
    _Float16* __restrict__ Xh, _Float16* __restrict__ Wt_qkv,
    _Float16* __restrict__ Wot) {
  int z = blockIdx.z;
  int t = threadIdx.x;
  if (z == 4) {  // x convert: 4096*1024 elems
    int id = blockIdx.y * 16 + blockIdx.x;
#pragma unroll
    for (int pass = 0; pass < 8; pass++) {
      size_t i = ((size_t)(pass * 256 + id) * 256 + t) * 8;
      float4 a = *(const float4*)&x[i];
      float4 b = *(const float4*)&x[i + 4];
      vhalf8 h;
      h[0] = (_Float16)a.x; h[1] = (_Float16)a.y;
      h[2] = (_Float16)a.z; h[3] = (_Float16)a.w;
      h[4] = (_Float16)b.x; h[5] = (_Float16)b.y;
      h[6] = (_Float16)b.z; h[7] = (_Float16)b.w;
      *(vhalf8*)&Xh[i] = h;
    }
    return;
  }
  __shared__ _Float16 tile[64][65];
  const float* in = (z == 0) ? Wq : (z == 1) ? Wk : (z == 2) ? Wv : Wo;
  _Float16* out = (z < 3) ? (Wt_qkv + (size_t)z * 1024 * 1024) : Wot;
  int c0 = blockIdx.x * 64, r0 = blockIdx.y * 64;
  int tc = t & 63, tr = t >> 6;
#pragma unroll
  for (int p = 0; p < 16; p++) {
    int r = tr + p * 4;
    tile[r][tc] = (_Float16)in[(size_t)(r0 + r) * 1024 + c0 + tc];
  }
  __syncthreads();
#pragma unroll
  for (int p = 0; p < 16; p++) {
    int r = tr + p * 4;
    out[(size_t)(c0 + r) * 1024 + r0 + tc] = tile[tc][r];
  }
}

// ---------------------------------------------------------------------------
// m97-style f16 GEMM: C[M][N] = A[M][K] @ Bt[N][K]^T.
// 128xBN tile, 4 waves, BK k-slab, global_load_lds width-16.
// mode 0: f16 out.  mode 1: f32 out.  mode 2 (QKV): f16 out, V cols
// (n >= 2048) written transposed into Vt[(b,h)][d][s].
// ---------------------------------------------------------------------------
template <int BN, int BK>
__global__ __launch_bounds__(256) void gemm128(
    const _Float16* __restrict__ A, const _Float16* __restrict__ Bt,
    _Float16* __restrict__ Ch, float* __restrict__ Cf,
    _Float16* __restrict__ Vt, int M, int N, int K, int mode) {
  constexpr int ACH = 128 * BK / 512;  // 1KB chunks of A
  constexpr int BCH = BN * BK / 512;
  constexpr int CPW = (ACH + BCH) / 4; // chunks per wave
  constexpr int RPC = 512 / BK;        // rows per chunk
  constexpr int LPR = BK / 8;          // lanes per row
  constexpr int JN = BN / 32;          // 16-col j-tiles per wave
  __shared__ _Float16 As[128 * BK];
  __shared__ _Float16 Bs[BN * BK];
  int m0 = blockIdx.x * 128, n0 = blockIdx.y * BN;
  int t = threadIdx.x;
  int lane = t & 63, wave = t >> 6;
  int wm = (wave >> 1) * 64, wn = (wave & 1) * (BN / 2);
  int col = lane & 15, quad = lane >> 4;
  int srow = lane / LPR;
  int skc = (lane % LPR) * 8;

  vfloat4 acc[4][JN];
#pragma unroll
  for (int i = 0; i < 4; i++)
#pragma unroll
    for (int j = 0; j < JN; j++) {
      acc[i][j][0] = 0.f; acc[i][j][1] = 0.f;
      acc[i][j][2] = 0.f; acc[i][j][3] = 0.f;
    }

  for (int k0 = 0; k0 < K; k0 += BK) {
    __syncthreads();
#pragma unroll
    for (int j = 0; j < CPW; j++) {
      int c = wave * CPW + j;
      if (c < ACH) {
        int row = c * RPC + srow;
        async16(&A[(size_t)(m0 + row) * K + k0 + skc], &As[c * 512]);
      } else {
        int row = (c - ACH) * RPC + srow;
        async16(&Bt[(size_t)(n0 + row) * K + k0 + skc], &Bs[(c - ACH) * 512]);
      }
    }
    __syncthreads();

#pragma unroll
    for (int sub = 0; sub < BK / 32; sub++) {
      vhalf8 af[4], bf[JN];
#pragma unroll
      for (int i = 0; i < 4; i++)
        af[i] = *(const vhalf8*)&As[(wm + i * 16 + col) * BK + sub * 32 + quad * 8];
#pragma unroll
      for (int j = 0; j < JN; j++)
        bf[j] = *(const vhalf8*)&Bs[(wn + j * 16 + col) * BK + sub * 32 + quad * 8];
#pragma unroll
      for (int i = 0; i < 4; i++)
#pragma unroll
        for (int j = 0; j < JN; j++)
          acc[i][j] = __builtin_amdgcn_mfma_f32_16x16x32_f16(af[i], bf[j], acc[i][j], 0, 0, 0);
    }
  }

  bool vmode = (mode == 2) && (n0 >= 2048);
#pragma unroll
  for (int i = 0; i < 4; i++)
#pragma unroll
    for (int j = 0; j < JN; j++)
#pragma unroll
      for (int r = 0; r < 4; r++) {
        int m = m0 + wm + i * 16 + quad * 4 + r;
        int n = n0 + wn + j * 16 + col;
        if (mode == 1) {
          Cf[(size_t)m * N + n] = acc[i][j][r];
        } else if (vmode) {
          int nn = n - 2048;
          int hh = nn >> 6, dd = nn & 63;
          int bb = m >> 11, ss = m & 2047;
          Vt[(((size_t)bb * NH + hh) * HD + dd) * SEQ + ss] = (_Float16)acc[i][j][r];
        } else {
          Ch[(size_t)m * N + n] = (_Float16)acc[i][j][r];
        }
      }
}

// ---------------------------------------------------------------------------
// Flash attention, causal, fixed-offset softmax.  4 waves (256 thr) / block,
// M=32 Q rows per wave (two row-groups share one K/V fragment register load
// -> halves LDS bytes per MFMA), 128 Q rows/block, 64-key LDS tiles,
// register-prefetch staging, CU-pair-balanced dispatch (qt pairs sum to 15).
// K rows staged permuted (slot 16*(kk&3)+(kk>>2)) so each lane's 4 P values
// are key-contiguous; staging columns XOR-swizzled to spread banks.
// ---------------------------------------------------------------------------
__global__ __launch_bounds__(256) void attn(
    const _Float16* __restrict__ QKV, const _Float16* __restrict__ Vt,
    _Float16* __restrict__ Vec) {
  int blk = blockIdx.x;
  int j = blk >> 5;
  int qt = (j < 8) ? (15 - j) : (j - 8);  // CU gets {15-k, k}: 36 iters const
  int hb = blk & 31;
  int h = hb & 15;
  int b = hb >> 4;
  int q0 = qt * 128;

  const _Float16* Qb  = QKV + (size_t)(b * SEQ) * 3072 + h * HD;
  const _Float16* Kb  = QKV + (size_t)(b * SEQ) * 3072 + 1024 + h * HD;
  const _Float16* Vtb = Vt + (size_t)(b * NH + h) * HD * SEQ;

  int t = threadIdx.x;
  int lane = t & 63, wave = t >> 6;
  int col = lane & 15, quad = lane >> 4;
  int wq0 = q0 + wave * 32;

  __shared__ _Float16 Ks[64][72];
  __shared__ _Float16 Vs[64][72];
  __shared__ _Float16 Ps[4][32][72];

  // Q fragments for two row groups, pre-scaled so softmax is bare exp2(s)
  vhalf8 qf[2][2];
#pragma unroll
  for (int g = 0; g < 2; g++) {
    qf[g][0] = *(const vhalf8*)&Qb[(size_t)(wq0 + g * 16 + col) * 3072 + quad * 8];
    qf[g][1] = *(const vhalf8*)&Qb[(size_t)(wq0 + g * 16 + col) * 3072 + 32 + quad * 8];
#pragma unroll
    for (int i = 0; i < 8; i++) {
      qf[g][0][i] = qf[g][0][i] * (_Float16)SCALE_K1;
      qf[g][1][i] = qf[g][1][i] * (_Float16)SCALE_K1;
    }
  }

  vfloat4 o[2][4];
#pragma unroll
  for (int g = 0; g < 2; g++)
#pragma unroll
    for (int i = 0; i < 4; i++) {
      o[g][i][0] = 0.f; o[g][i][1] = 0.f; o[g][i][2] = 0.f; o[g][i][3] = 0.f;
    }
  float lsum[2][4] = {{0.f, 0.f, 0.f, 0.f}, {0.f, 0.f, 0.f, 0.f}};

  // staging: 256 threads, two vhalf8 of K and two of V each
  int srow = t >> 2;                    // 0..63
  int scol = (t & 3) * 16;
  int kslot = ((srow & 3) << 4) + (srow >> 2);
  int kcol = scol ^ ((srow & 3) << 4);  // XOR swizzle

  vhalf8 kr0, kr1, vr0, vr1;
  {
    const _Float16* kg = &Kb[(size_t)srow * 3072 + scol];
    kr0 = *(const vhalf8*)kg; kr1 = *(const vhalf8*)(kg + 8);
    const _Float16* vg = &Vtb[(size_t)srow * SEQ + scol];
    vr0 = *(const vhalf8*)vg; vr1 = *(const vhalf8*)(vg + 8);
  }

  for (int kb = 0; kb <= q0 + 127; kb += 64) {
    *(vhalf8*)&Ks[kslot][kcol]     = kr0;
    *(vhalf8*)&Ks[kslot][kcol + 8] = kr1;
    *(vhalf8*)&Vs[srow][scol]      = vr0;
    *(vhalf8*)&Vs[srow][scol + 8]  = vr1;
    __syncthreads();

    if (kb < q0 + 64) {  // prefetch next tile; overlaps compute
      const _Float16* kg = &Kb[(size_t)(kb + 64 + srow) * 3072 + scol];
      kr0 = *(const vhalf8*)kg; kr1 = *(const vhalf8*)(kg + 8);
      const _Float16* vg = &Vtb[(size_t)srow * SEQ + kb + 64 + scol];
      vr0 = *(const vhalf8*)vg; vr1 = *(const vhalf8*)(vg + 8);
    }

    if (kb <= wq0 + 31) {  // wave-uniform compute guard
      // K fragments loaded ONCE, reused by both row groups
      vhalf8 kf[4][2];
#pragma unroll
      for (int hh = 0; hh < 4; hh++) {
        int sw = hh << 4;
        kf[hh][0] = *(const vhalf8*)&Ks[hh * 16 + col][(quad * 8) ^ sw];
        kf[hh][1] = *(const vhalf8*)&Ks[hh * 16 + col][(32 + quad * 8) ^ sw];
      }
#pragma unroll
      for (int g = 0; g < 2; g++) {
        vfloat4 s[4];
#pragma unroll
        for (int hh = 0; hh < 4; hh++) {
          vfloat4 z; z[0]=0.f; z[1]=0.f; z[2]=0.f; z[3]=0.f;
          z = __builtin_amdgcn_mfma_f32_16x16x32_f16(qf[g][0], kf[hh][0], z, 0, 0, 0);
          z = __builtin_amdgcn_mfma_f32_16x16x32_f16(qf[g][1], kf[hh][1], z, 0, 0, 0);
          s[hh] = z;
        }
        bool diag = (kb + 63 > wq0 + g * 16);
#pragma unroll
        for (int r = 0; r < 4; r++) {
          int q = wq0 + g * 16 + quad * 4 + r;
          float p[4];
#pragma unroll
          for (int hh = 0; hh < 4; hh++) {
            float sc = s[hh][r];
            if (diag && (kb + 4 * col + hh > q)) sc = -1e30f;
            p[hh] = __builtin_exp2f(sc);
          }
          lsum[g][r] += (p[0] + p[1]) + (p[2] + p[3]);
          vhalf4 ph;
          ph[0] = (_Float16)p[0]; ph[1] = (_Float16)p[1];
          ph[2] = (_Float16)p[2]; ph[3] = (_Float16)p[3];
          *(vhalf4*)&Ps[wave][g * 16 + quad * 4 + r][4 * col] = ph;
        }
      }
      // P write->read is wave-local; LDS drain only, no block barrier
      __asm__ __volatile__("s_waitcnt lgkmcnt(0)" ::: "memory");
      // V fragments loaded ONCE, reused by both row groups
      vhalf8 vf[4][2];
#pragma unroll
      for (int tt = 0; tt < 4; tt++) {
        vf[tt][0] = *(const vhalf8*)&Vs[tt * 16 + col][quad * 8];
        vf[tt][1] = *(const vhalf8*)&Vs[tt * 16 + col][32 + quad * 8];
      }
#pragma unroll
      for (int g = 0; g < 2; g++) {
        vhalf8 pf0 = *(const vhalf8*)&Ps[wave][g * 16 + col][quad * 8];
        vhalf8 pf1 = *(const vhalf8*)&Ps[wave][g * 16 + col][32 + quad * 8];
#pragma unroll
        for (int tt = 0; tt < 4; tt++) {
          o[g][tt] = __builtin_amdgcn_mfma_f32_16x16x32_f16(pf0, vf[tt][0], o[g][tt], 0, 0, 0);
          o[g][tt] = __builtin_amdgcn_mfma_f32_16x16x32_f16(pf1, vf[tt][1], o[g][tt], 0, 0, 0);
        }
      }
    }
    __syncthreads();
  }

#pragma unroll
  for (int g = 0; g < 2; g++) {
    float inv_l[4];
#pragma unroll
    for (int r = 0; r < 4; r++) {
      float rs = lsum[g][r];
#pragma unroll
      for (int msk = 1; msk < 16; msk <<= 1) rs += __shfl_xor(rs, msk, 64);
      inv_l[r] = 1.0f / rs;
    }
#pragma unroll
    for (int tt = 0; tt < 4; tt++)
#pragma unroll
      for (int r = 0; r < 4; r++) {
        int q = wq0 + g * 16 + quad * 4 + r;
        int d = tt * 16 + col;
        Vec[(size_t)(b * SEQ + q) * D_MODEL + h * HD + d] =
            (_Float16)(o[g][tt][r] * inv_l[r]);
      }
  }
}

// ---------------------------------------------------------------------------
extern "C" void kernel_launch(void* const* d_in, const int* in_sizes, int n_in,
                              void* d_out, int out_size, void* d_ws, size_t ws_size,
                              hipStream_t stream) {
  const float* x  = (const float*)d_in[0];
  const float* Wq = (const float*)d_in[1];
  const float* Wk = (const float*)d_in[2];
  const float* Wv = (const float*)d_in[3];
  const float* Wo = (const float*)d_in[4];
  float* out = (float*)d_out;

  char* ws = (char*)d_ws;
  _Float16* Xh     = (_Float16*)ws;                    // [4096][1024]   8 MiB
  _Float16* Wt_qkv = (_Float16*)(ws + 8388608);        // [3072][1024]   6 MiB
  _Float16* Wot    = (_Float16*)(ws + 14680064);       // [1024][1024]   2 MiB
  _Float16* QKV    = (_Float16*)(ws + 16777216);       // [4096][3072]  24 MiB (V region unused)
  _Float16* Vt     = (_Float16*)(ws + 41943040);       // [32][64][2048] 8 MiB
  _Float16* Vec    = (_Float16*)(ws + 50331648);       // [4096][1024]   8 MiB

  dim3 tb(256);
  prep<<<dim3(16, 16, 5), tb, 0, stream>>>(x, Wq, Wk, Wv, Wo, Xh, Wt_qkv, Wot);
  gemm128<128, 64><<<dim3(32, 24), tb, 0, stream>>>(Xh, Wt_qkv, QKV, nullptr, Vt,
                                                    4096, 3072, 1024, 2);
  attn<<<dim3(512), tb, 0, stream>>>(QKV, Vt, Vec);
  gemm128<64, 64><<<dim3(32, 16), tb, 0, stream>>>(Vec, Wot, nullptr, out, nullptr,
                                                   4096, 1024, 1024, 1);
}

// Round 9
// 197.942 us; speedup vs baseline: 1.1525x; 1.1525x over previous
//
#include <hip/hip_runtime.h>
#include <hip/hip_bf16.h>

// fp32 I/O, fp16 MFMA compute (verified: absmax 3.9e-3 vs thr 3.1e-2).
// R9: GEMM back to BK=32 (BK=64's 128B row stride = 16-way LDS conflicts,
//     m132 lesson confirmed by 9.4M SQ_LDS_BANK_CONFLICT) + global-source
//     XOR swizzle so fragment reads are 4-way instead of 8-way.
//     attn unchanged from R8 (M=32/wave; left the top-5).

typedef __attribute__((ext_vector_type(8))) _Float16 vhalf8;
typedef __attribute__((ext_vector_type(4))) _Float16 vhalf4;
typedef __attribute__((ext_vector_type(4))) float vfloat4;

#define D_MODEL 1024
#define SEQ     2048
#define NB      2
#define NH      16
#define HD      64

// softmax: exp(s/8) = exp2(s * 0.125*log2(e)); constant offset cancels in o/l.
#define SCALE_K1 0.18033688f

__device__ __forceinline__ void async16(const void* g, void* l) {
  __builtin_amdgcn_global_load_lds(
      (const __attribute__((address_space(1))) unsigned int*)g,
      (__attribute__((address_space(3))) unsigned int*)l, 16, 0, 0);
}

// ---------------------------------------------------------------------------
// prep: z<4 -> weight transpose+convert planes; z==4 -> x fp32->fp16 convert.
// ---------------------------------------------------------------------------
__global__ __launch_bounds__(256) void prep(
    const float* __restrict__ x,
    const float* __restrict__ Wq, const float* __restrict__ Wk,
    const float* __restrict__ Wv, const float* __restrict__ Wo,
    _Float16* __restrict__ Xh, _Float16* __restrict__ Wt_qkv,
    _Float16* __restrict__ Wot) {
  int z = blockIdx.z;
  int t = threadIdx.x;
  if (z == 4) {  // x convert: 4096*1024 elems
    int id = blockIdx.y * 16 + blockIdx.x;
#pragma unroll
    for (int pass = 0; pass < 8; pass++) {
      size_t i = ((size_t)(pass * 256 + id) * 256 + t) * 8;
      float4 a = *(const float4*)&x[i];
      float4 b = *(const float4*)&x[i + 4];
      vhalf8 h;
      h[0] = (_Float16)a.x; h[1] = (_Float16)a.y;
      h[2] = (_Float16)a.z; h[3] = (_Float16)a.w;
      h[4] = (_Float16)b.x; h[5] = (_Float16)b.y;
      h[6] = (_Float16)b.z; h[7] = (_Float16)b.w;
      *(vhalf8*)&Xh[i] = h;
    }
    return;
  }
  __shared__ _Float16 tile[64][65];
  const float* in = (z == 0) ? Wq : (z == 1) ? Wk : (z == 2) ? Wv : Wo;
  _Float16* out = (z < 3) ? (Wt_qkv + (size_t)z * 1024 * 1024) : Wot;
  int c0 = blockIdx.x * 64, r0 = blockIdx.y * 64;
  int tc = t & 63, tr = t >> 6;
#pragma unroll
  for (int p = 0; p < 16; p++) {
    int r = tr + p * 4;
    tile[r][tc] = (_Float16)in[(size_t)(r0 + r) * 1024 + c0 + tc];
  }
  __syncthreads();
#pragma unroll
  for (int p = 0; p < 16; p++) {
    int r = tr + p * 4;
    out[(size_t)(c0 + r) * 1024 + r0 + tc] = tile[tc][r];
  }
}

// ---------------------------------------------------------------------------
// m97-style f16 GEMM: C[M][N] = A[M][K] @ Bt[N][K]^T.
// 128xBN tile, 4 waves, BK=32, global_load_lds width-16.
// Slot swizzle: lane with staging row srow loads global k-slot
// (slot ^ (srow&3)); fragment read un-swizzles with xq = quad ^ (row&3).
// Cuts fragment-read bank conflicts 8-way -> 4-way while keeping the
// wave-uniform-base contiguity global_load_lds requires.
// mode 0: f16 out.  mode 1: f32 out.  mode 2 (QKV): f16 out, V cols
// (n >= 2048) written transposed into Vt[(b,h)][d][s].
// ---------------------------------------------------------------------------
template <int BN>
__global__ __launch_bounds__(256) void gemm128(
    const _Float16* __restrict__ A, const _Float16* __restrict__ Bt,
    _Float16* __restrict__ Ch, float* __restrict__ Cf,
    _Float16* __restrict__ Vt, int M, int N, int K, int mode) {
  constexpr int ACH = 8;                // A chunks (128 rows / 16 per 1KB chunk)
  constexpr int BCH = BN / 16;          // B chunks
  constexpr int CPW = (ACH + BCH) / 4;  // chunks per wave
  constexpr int JN = BN / 32;           // 16-col j-tiles per wave
  __shared__ _Float16 As[128 * 32];
  __shared__ _Float16 Bs[BN * 32];
  int m0 = blockIdx.x * 128, n0 = blockIdx.y * BN;
  int t = threadIdx.x;
  int lane = t & 63, wave = t >> 6;
  int wm = (wave >> 1) * 64, wn = (wave & 1) * (BN / 2);
  int col = lane & 15, quad = lane >> 4;
  int srow = lane >> 2;                       // 0..15 within chunk
  int gcol = (((lane & 3) ^ (srow & 3)) << 3);  // swizzled global k-slot

  vfloat4 acc[4][JN];
#pragma unroll
  for (int i = 0; i < 4; i++)
#pragma unroll
    for (int j = 0; j < JN; j++) {
      acc[i][j][0] = 0.f; acc[i][j][1] = 0.f;
      acc[i][j][2] = 0.f; acc[i][j][3] = 0.f;
    }

  int xq = (quad ^ (col & 3)) * 8;  // un-swizzled fragment k-slot (elems)

  for (int k0 = 0; k0 < K; k0 += 32) {
    __syncthreads();
#pragma unroll
    for (int j = 0; j < CPW; j++) {
      int c = wave * CPW + j;
      if (c < ACH) {
        int row = c * 16 + srow;
        async16(&A[(size_t)(m0 + row) * K + k0 + gcol], &As[c * 512]);
      } else {
        int row = (c - ACH) * 16 + srow;
        async16(&Bt[(size_t)(n0 + row) * K + k0 + gcol], &Bs[(c - ACH) * 512]);
      }
    }
    __syncthreads();

    vhalf8 af[4], bf[JN];
#pragma unroll
    for (int i = 0; i < 4; i++)
      af[i] = *(const vhalf8*)&As[(wm + i * 16 + col) * 32 + xq];
#pragma unroll
    for (int j = 0; j < JN; j++)
      bf[j] = *(const vhalf8*)&Bs[(wn + j * 16 + col) * 32 + xq];
#pragma unroll
    for (int i = 0; i < 4; i++)
#pragma unroll
      for (int j = 0; j < JN; j++)
        acc[i][j] = __builtin_amdgcn_mfma_f32_16x16x32_f16(af[i], bf[j], acc[i][j], 0, 0, 0);
  }

  bool vmode = (mode == 2) && (n0 >= 2048);
#pragma unroll
  for (int i = 0; i < 4; i++)
#pragma unroll
    for (int j = 0; j < JN; j++)
#pragma unroll
      for (int r = 0; r < 4; r++) {
        int m = m0 + wm + i * 16 + quad * 4 + r;
        int n = n0 + wn + j * 16 + col;
        if (mode == 1) {
          Cf[(size_t)m * N + n] = acc[i][j][r];
        } else if (vmode) {
          int nn = n - 2048;
          int hh = nn >> 6, dd = nn & 63;
          int bb = m >> 11, ss = m & 2047;
          Vt[(((size_t)bb * NH + hh) * HD + dd) * SEQ + ss] = (_Float16)acc[i][j][r];
        } else {
          Ch[(size_t)m * N + n] = (_Float16)acc[i][j][r];
        }
      }
}

// ---------------------------------------------------------------------------
// Flash attention, causal, fixed-offset softmax.  4 waves (256 thr) / block,
// M=32 Q rows per wave (two row-groups share one K/V fragment register load),
// 128 Q rows/block, 64-key LDS tiles, register-prefetch staging,
// CU-pair-balanced dispatch (qt pairs sum to 15 -> 36 iters const).
// ---------------------------------------------------------------------------
__global__ __launch_bounds__(256) void attn(
    const _Float16* __restrict__ QKV, const _Float16* __restrict__ Vt,
    _Float16* __restrict__ Vec) {
  int blk = blockIdx.x;
  int j = blk >> 5;
  int qt = (j < 8) ? (15 - j) : (j - 8);
  int hb = blk & 31;
  int h = hb & 15;
  int b = hb >> 4;
  int q0 = qt * 128;

  const _Float16* Qb  = QKV + (size_t)(b * SEQ) * 3072 + h * HD;
  const _Float16* Kb  = QKV + (size_t)(b * SEQ) * 3072 + 1024 + h * HD;
  const _Float16* Vtb = Vt + (size_t)(b * NH + h) * HD * SEQ;

  int t = threadIdx.x;
  int lane = t & 63, wave = t >> 6;
  int col = lane & 15, quad = lane >> 4;
  int wq0 = q0 + wave * 32;

  __shared__ _Float16 Ks[64][72];
  __shared__ _Float16 Vs[64][72];
  __shared__ _Float16 Ps[4][32][72];

  vhalf8 qf[2][2];
#pragma unroll
  for (int g = 0; g < 2; g++) {
    qf[g][0] = *(const vhalf8*)&Qb[(size_t)(wq0 + g * 16 + col) * 3072 + quad * 8];
    qf[g][1] = *(const vhalf8*)&Qb[(size_t)(wq0 + g * 16 + col) * 3072 + 32 + quad * 8];
#pragma unroll
    for (int i = 0; i < 8; i++) {
      qf[g][0][i] = qf[g][0][i] * (_Float16)SCALE_K1;
      qf[g][1][i] = qf[g][1][i] * (_Float16)SCALE_K1;
    }
  }

  vfloat4 o[2][4];
#pragma unroll
  for (int g = 0; g < 2; g++)
#pragma unroll
    for (int i = 0; i < 4; i++) {
      o[g][i][0] = 0.f; o[g][i][1] = 0.f; o[g][i][2] = 0.f; o[g][i][3] = 0.f;
    }
  float lsum[2][4] = {{0.f, 0.f, 0.f, 0.f}, {0.f, 0.f, 0.f, 0.f}};

  int srow = t >> 2;
  int scol = (t & 3) * 16;
  int kslot = ((srow & 3) << 4) + (srow >> 2);
  int kcol = scol ^ ((srow & 3) << 4);

  vhalf8 kr0, kr1, vr0, vr1;
  {
    const _Float16* kg = &Kb[(size_t)srow * 3072 + scol];
    kr0 = *(const vhalf8*)kg; kr1 = *(const vhalf8*)(kg + 8);
    const _Float16* vg = &Vtb[(size_t)srow * SEQ + scol];
    vr0 = *(const vhalf8*)vg; vr1 = *(const vhalf8*)(vg + 8);
  }

  for (int kb = 0; kb <= q0 + 127; kb += 64) {
    *(vhalf8*)&Ks[kslot][kcol]     = kr0;
    *(vhalf8*)&Ks[kslot][kcol + 8] = kr1;
    *(vhalf8*)&Vs[srow][scol]      = vr0;
    *(vhalf8*)&Vs[srow][scol + 8]  = vr1;
    __syncthreads();

    if (kb < q0 + 64) {
      const _Float16* kg = &Kb[(size_t)(kb + 64 + srow) * 3072 + scol];
      kr0 = *(const vhalf8*)kg; kr1 = *(const vhalf8*)(kg + 8);
      const _Float16* vg = &Vtb[(size_t)srow * SEQ + kb + 64 + scol];
      vr0 = *(const vhalf8*)vg; vr1 = *(const vhalf8*)(vg + 8);
    }

    if (kb <= wq0 + 31) {
      vhalf8 kf[4][2];
#pragma unroll
      for (int hh = 0; hh < 4; hh++) {
        int sw = hh << 4;
        kf[hh][0] = *(const vhalf8*)&Ks[hh * 16 + col][(quad * 8) ^ sw];
        kf[hh][1] = *(const vhalf8*)&Ks[hh * 16 + col][(32 + quad * 8) ^ sw];
      }
#pragma unroll
      for (int g = 0; g < 2; g++) {
        vfloat4 s[4];
#pragma unroll
        for (int hh = 0; hh < 4; hh++) {
          vfloat4 z; z[0]=0.f; z[1]=0.f; z[2]=0.f; z[3]=0.f;
          z = __builtin_amdgcn_mfma_f32_16x16x32_f16(qf[g][0], kf[hh][0], z, 0, 0, 0);
          z = __builtin_amdgcn_mfma_f32_16x16x32_f16(qf[g][1], kf[hh][1], z, 0, 0, 0);
          s[hh] = z;
        }
        bool diag = (kb + 63 > wq0 + g * 16);
#pragma unroll
        for (int r = 0; r < 4; r++) {
          int q = wq0 + g * 16 + quad * 4 + r;
          float p[4];
#pragma unroll
          for (int hh = 0; hh < 4; hh++) {
            float sc = s[hh][r];
            if (diag && (kb + 4 * col + hh > q)) sc = -1e30f;
            p[hh] = __builtin_exp2f(sc);
          }
          lsum[g][r] += (p[0] + p[1]) + (p[2] + p[3]);
          vhalf4 ph;
          ph[0] = (_Float16)p[0]; ph[1] = (_Float16)p[1];
          ph[2] = (_Float16)p[2]; ph[3] = (_Float16)p[3];
          *(vhalf4*)&Ps[wave][g * 16 + quad * 4 + r][4 * col] = ph;
        }
      }
      __asm__ __volatile__("s_waitcnt lgkmcnt(0)" ::: "memory");
      vhalf8 vf[4][2];
#pragma unroll
      for (int tt = 0; tt < 4; tt++) {
        vf[tt][0] = *(const vhalf8*)&Vs[tt * 16 + col][quad * 8];
        vf[tt][1] = *(const vhalf8*)&Vs[tt * 16 + col][32 + quad * 8];
      }
#pragma unroll
      for (int g = 0; g < 2; g++) {
        vhalf8 pf0 = *(const vhalf8*)&Ps[wave][g * 16 + col][quad * 8];
        vhalf8 pf1 = *(const vhalf8*)&Ps[wave][g * 16 + col][32 + quad * 8];
#pragma unroll
        for (int tt = 0; tt < 4; tt++) {
          o[g][tt] = __builtin_amdgcn_mfma_f32_16x16x32_f16(pf0, vf[tt][0], o[g][tt], 0, 0, 0);
          o[g][tt] = __builtin_amdgcn_mfma_f32_16x16x32_f16(pf1, vf[tt][1], o[g][tt], 0, 0, 0);
        }
      }
    }
    __syncthreads();
  }

#pragma unroll
  for (int g = 0; g < 2; g++) {
    float inv_l[4];
#pragma unroll
    for (int r = 0; r < 4; r++) {
      float rs = lsum[g][r];
#pragma unroll
      for (int msk = 1; msk < 16; msk <<= 1) rs += __shfl_xor(rs, msk, 64);
      inv_l[r] = 1.0f / rs;
    }
#pragma unroll
    for (int tt = 0; tt < 4; tt++)
#pragma unroll
      for (int r = 0; r < 4; r++) {
        int q = wq0 + g * 16 + quad * 4 + r;
        int d = tt * 16 + col;
        Vec[(size_t)(b * SEQ + q) * D_MODEL + h * HD + d] =
            (_Float16)(o[g][tt][r] * inv_l[r]);
      }
  }
}

// ---------------------------------------------------------------------------
extern "C" void kernel_launch(void* const* d_in, const int* in_sizes, int n_in,
                              void* d_out, int out_size, void* d_ws, size_t ws_size,
                              hipStream_t stream) {
  const float* x  = (const float*)d_in[0];
  const float* Wq = (const float*)d_in[1];
  const float* Wk = (const float*)d_in[2];
  const float* Wv = (const float*)d_in[3];
  const float* Wo = (const float*)d_in[4];
  float* out = (float*)d_out;

  char* ws = (char*)d_ws;
  _Float16* Xh     = (_Float16*)ws;                    // [4096][1024]   8 MiB
  _Float16* Wt_qkv = (_Float16*)(ws + 8388608);        // [3072][1024]   6 MiB
  _Float16* Wot    = (_Float16*)(ws + 14680064);       // [1024][1024]   2 MiB
  _Float16* QKV    = (_Float16*)(ws + 16777216);       // [4096][3072]  24 MiB (V region unused)
  _Float16* Vt     = (_Float16*)(ws + 41943040);       // [32][64][2048] 8 MiB
  _Float16* Vec    = (_Float16*)(ws + 50331648);       // [4096][1024]   8 MiB

  dim3 tb(256);
  prep<<<dim3(16, 16, 5), tb, 0, stream>>>(x, Wq, Wk, Wv, Wo, Xh, Wt_qkv, Wot);
  gemm128<128><<<dim3(32, 24), tb, 0, stream>>>(Xh, Wt_qkv, QKV, nullptr, Vt,
                                                4096, 3072, 1024, 2);
  attn<<<dim3(512), tb, 0, stream>>>(QKV, Vt, Vec);
  gemm128<64><<<dim3(32, 16), tb, 0, stream>>>(Vec, Wot, nullptr, out, nullptr,
                                               4096, 1024, 1024, 1);
}

// Round 10
// 192.682 us; speedup vs baseline: 1.1840x; 1.0273x over previous
//
#include <hip/hip_runtime.h>
#include <hip/hip_bf16.h>

// fp32 I/O, fp16 MFMA compute (verified: absmax 3.9e-3 vs thr 3.1e-2).
// R10: attn back to M=16/wave (latency-bound, needs waves not fewer LDS
//      bytes — R9 post-mortem), uniform-work blocks: each block runs two
//      64-row q-tiles (31-pp then pp) = 33 iters for EVERY block. 8 waves/CU
//      steady, no tail, dispatch-order-robust. GEMM/prep unchanged from R9.

typedef __attribute__((ext_vector_type(8))) _Float16 vhalf8;
typedef __attribute__((ext_vector_type(4))) _Float16 vhalf4;
typedef __attribute__((ext_vector_type(4))) float vfloat4;

#define D_MODEL 1024
#define SEQ     2048
#define NB      2
#define NH      16
#define HD      64

// softmax: exp(s/8) = exp2(s * 0.125*log2(e)); constant offset cancels in o/l.
#define SCALE_K1 0.18033688f

__device__ __forceinline__ void async16(const void* g, void* l) {
  __builtin_amdgcn_global_load_lds(
      (const __attribute__((address_space(1))) unsigned int*)g,
      (__attribute__((address_space(3))) unsigned int*)l, 16, 0, 0);
}

// ---------------------------------------------------------------------------
// prep: z<4 -> weight transpose+convert planes; z==4 -> x fp32->fp16 convert.
// ---------------------------------------------------------------------------
__global__ __launch_bounds__(256) void prep(
    const float* __restrict__ x,
    const float* __restrict__ Wq, const float* __restrict__ Wk,
    const float* __restrict__ Wv, const float* __restrict__ Wo,
    _Float16* __restrict__ Xh, _Float16* __restrict__ Wt_qkv,
    _Float16* __restrict__ Wot) {
  int z = blockIdx.z;
  int t = threadIdx.x;
  if (z == 4) {  // x convert: 4096*1024 elems
    int id = blockIdx.y * 16 + blockIdx.x;
#pragma unroll
    for (int pass = 0; pass < 8; pass++) {
      size_t i = ((size_t)(pass * 256 + id) * 256 + t) * 8;
      float4 a = *(const float4*)&x[i];
      float4 b = *(const float4*)&x[i + 4];
      vhalf8 h;
      h[0] = (_Float16)a.x; h[1] = (_Float16)a.y;
      h[2] = (_Float16)a.z; h[3] = (_Float16)a.w;
      h[4] = (_Float16)b.x; h[5] = (_Float16)b.y;
      h[6] = (_Float16)b.z; h[7] = (_Float16)b.w;
      *(vhalf8*)&Xh[i] = h;
    }
    return;
  }
  __shared__ _Float16 tile[64][65];
  const float* in = (z == 0) ? Wq : (z == 1) ? Wk : (z == 2) ? Wv : Wo;
  _Float16* out = (z < 3) ? (Wt_qkv + (size_t)z * 1024 * 1024) : Wot;
  int c0 = blockIdx.x * 64, r0 = blockIdx.y * 64;
  int tc = t & 63, tr = t >> 6;
#pragma unroll
  for (int p = 0; p < 16; p++) {
    int r = tr + p * 4;
    tile[r][tc] = (_Float16)in[(size_t)(r0 + r) * 1024 + c0 + tc];
  }
  __syncthreads();
#pragma unroll
  for (int p = 0; p < 16; p++) {
    int r = tr + p * 4;
    out[(size_t)(c0 + r) * 1024 + r0 + tc] = tile[tc][r];
  }
}

// ---------------------------------------------------------------------------
// m97-style f16 GEMM: C[M][N] = A[M][K] @ Bt[N][K]^T.
// 128xBN tile, 4 waves, BK=32, global_load_lds width-16, XOR slot swizzle
// (fragment reads 4-way instead of 8-way conflicts).
// mode 0: f16 out.  mode 1: f32 out.  mode 2 (QKV): f16 out, V cols
// (n >= 2048) written transposed into Vt[(b,h)][d][s].
// ---------------------------------------------------------------------------
template <int BN>
__global__ __launch_bounds__(256) void gemm128(
    const _Float16* __restrict__ A, const _Float16* __restrict__ Bt,
    _Float16* __restrict__ Ch, float* __restrict__ Cf,
    _Float16* __restrict__ Vt, int M, int N, int K, int mode) {
  constexpr int ACH = 8;
  constexpr int BCH = BN / 16;
  constexpr int CPW = (ACH + BCH) / 4;
  constexpr int JN = BN / 32;
  __shared__ _Float16 As[128 * 32];
  __shared__ _Float16 Bs[BN * 32];
  int m0 = blockIdx.x * 128, n0 = blockIdx.y * BN;
  int t = threadIdx.x;
  int lane = t & 63, wave = t >> 6;
  int wm = (wave >> 1) * 64, wn = (wave & 1) * (BN / 2);
  int col = lane & 15, quad = lane >> 4;
  int srow = lane >> 2;
  int gcol = (((lane & 3) ^ (srow & 3)) << 3);

  vfloat4 acc[4][JN];
#pragma unroll
  for (int i = 0; i < 4; i++)
#pragma unroll
    for (int j = 0; j < JN; j++) {
      acc[i][j][0] = 0.f; acc[i][j][1] = 0.f;
      acc[i][j][2] = 0.f; acc[i][j][3] = 0.f;
    }

  int xq = (quad ^ (col & 3)) * 8;

  for (int k0 = 0; k0 < K; k0 += 32) {
    __syncthreads();
#pragma unroll
    for (int j = 0; j < CPW; j++) {
      int c = wave * CPW + j;
      if (c < ACH) {
        int row = c * 16 + srow;
        async16(&A[(size_t)(m0 + row) * K + k0 + gcol], &As[c * 512]);
      } else {
        int row = (c - ACH) * 16 + srow;
        async16(&Bt[(size_t)(n0 + row) * K + k0 + gcol], &Bs[(c - ACH) * 512]);
      }
    }
    __syncthreads();

    vhalf8 af[4], bf[JN];
#pragma unroll
    for (int i = 0; i < 4; i++)
      af[i] = *(const vhalf8*)&As[(wm + i * 16 + col) * 32 + xq];
#pragma unroll
    for (int j = 0; j < JN; j++)
      bf[j] = *(const vhalf8*)&Bs[(wn + j * 16 + col) * 32 + xq];
#pragma unroll
    for (int i = 0; i < 4; i++)
#pragma unroll
      for (int j = 0; j < JN; j++)
        acc[i][j] = __builtin_amdgcn_mfma_f32_16x16x32_f16(af[i], bf[j], acc[i][j], 0, 0, 0);
  }

  bool vmode = (mode == 2) && (n0 >= 2048);
#pragma unroll
  for (int i = 0; i < 4; i++)
#pragma unroll
    for (int j = 0; j < JN; j++)
#pragma unroll
      for (int r = 0; r < 4; r++) {
        int m = m0 + wm + i * 16 + quad * 4 + r;
        int n = n0 + wn + j * 16 + col;
        if (mode == 1) {
          Cf[(size_t)m * N + n] = acc[i][j][r];
        } else if (vmode) {
          int nn = n - 2048;
          int hh = nn >> 6, dd = nn & 63;
          int bb = m >> 11, ss = m & 2047;
          Vt[(((size_t)bb * NH + hh) * HD + dd) * SEQ + ss] = (_Float16)acc[i][j][r];
        } else {
          Ch[(size_t)m * N + n] = (_Float16)acc[i][j][r];
        }
      }
}

// ---------------------------------------------------------------------------
// Flash attention, causal, fixed-offset softmax.
// 4 waves (256 thr)/block, M=16 Q rows per wave, 64-key LDS tiles.
// UNIFORM WORK: each block processes two 64-row q-tiles sequentially
// (tile 31-pp then tile pp) -> exactly 33 key-tile iters per block.
// Grid 512 = 2 blocks/CU, 8 waves/CU steady, no drain tail, robust to
// any dispatch order. Cross-phase K/V register prefetch.
// ---------------------------------------------------------------------------
__global__ __launch_bounds__(256) void attn(
    const _Float16* __restrict__ QKV, const _Float16* __restrict__ Vt,
    _Float16* __restrict__ Vec) {
  int blk = blockIdx.x;
  int pp = blk >> 5;            // 0..15
  int hb = blk & 31;
  int h = hb & 15;
  int b = hb >> 4;

  const _Float16* Qb  = QKV + (size_t)(b * SEQ) * 3072 + h * HD;
  const _Float16* Kb  = QKV + (size_t)(b * SEQ) * 3072 + 1024 + h * HD;
  const _Float16* Vtb = Vt + (size_t)(b * NH + h) * HD * SEQ;

  int t = threadIdx.x;
  int lane = t & 63, wave = t >> 6;
  int col = lane & 15, quad = lane >> 4;

  __shared__ _Float16 Ks[64][72];
  __shared__ _Float16 Vs[64][72];
  __shared__ _Float16 Ps[4][16][72];

  int srow = t >> 2;
  int scol = (t & 3) * 16;
  int kslot = ((srow & 3) << 4) + (srow >> 2);   // K row permutation
  int kcol = scol ^ ((srow & 3) << 4);           // XOR bank swizzle

  int tiles[2] = {31 - pp, pp};

  // prologue prefetch: phase 0, kb = 0
  vhalf8 kr0, kr1, vr0, vr1;
  {
    const _Float16* kg = &Kb[(size_t)srow * 3072 + scol];
    kr0 = *(const vhalf8*)kg; kr1 = *(const vhalf8*)(kg + 8);
    const _Float16* vg = &Vtb[(size_t)srow * SEQ + scol];
    vr0 = *(const vhalf8*)vg; vr1 = *(const vhalf8*)(vg + 8);
  }

#pragma unroll
  for (int phase = 0; phase < 2; phase++) {
    int q0 = tiles[phase] * 64;
    int wq0 = q0 + wave * 16;

    // Q fragments, pre-scaled so softmax is bare exp2(s)
    vhalf8 qf0 = *(const vhalf8*)&Qb[(size_t)(wq0 + col) * 3072 + quad * 8];
    vhalf8 qf1 = *(const vhalf8*)&Qb[(size_t)(wq0 + col) * 3072 + 32 + quad * 8];
#pragma unroll
    for (int i = 0; i < 8; i++) {
      qf0[i] = qf0[i] * (_Float16)SCALE_K1;
      qf1[i] = qf1[i] * (_Float16)SCALE_K1;
    }

    vfloat4 o[4];
#pragma unroll
    for (int i = 0; i < 4; i++) { o[i][0]=0.f; o[i][1]=0.f; o[i][2]=0.f; o[i][3]=0.f; }
    float lsum[4] = {0.f, 0.f, 0.f, 0.f};

    for (int kb = 0; kb <= q0; kb += 64) {
      *(vhalf8*)&Ks[kslot][kcol]     = kr0;
      *(vhalf8*)&Ks[kslot][kcol + 8] = kr1;
      *(vhalf8*)&Vs[srow][scol]      = vr0;
      *(vhalf8*)&Vs[srow][scol + 8]  = vr1;
      __syncthreads();

      // prefetch next tile (next kb, or next phase's kb=0); overlaps compute
      int nxt = (kb < q0) ? (kb + 64) : ((phase == 0) ? 0 : -1);
      if (nxt >= 0) {
        const _Float16* kg = &Kb[(size_t)(nxt + srow) * 3072 + scol];
        kr0 = *(const vhalf8*)kg; kr1 = *(const vhalf8*)(kg + 8);
        const _Float16* vg = &Vtb[(size_t)srow * SEQ + nxt + scol];
        vr0 = *(const vhalf8*)vg; vr1 = *(const vhalf8*)(vg + 8);
      }

      // QK^T: 16 rows x 64 keys (K rows permuted: frag tile hh row c = key 4c+hh)
      vhalf8 kf[4][2];
#pragma unroll
      for (int hh = 0; hh < 4; hh++) {
        int sw = hh << 4;
        kf[hh][0] = *(const vhalf8*)&Ks[hh * 16 + col][(quad * 8) ^ sw];
        kf[hh][1] = *(const vhalf8*)&Ks[hh * 16 + col][(32 + quad * 8) ^ sw];
      }
      vfloat4 s[4];
#pragma unroll
      for (int hh = 0; hh < 4; hh++) {
        vfloat4 z; z[0]=0.f; z[1]=0.f; z[2]=0.f; z[3]=0.f;
        z = __builtin_amdgcn_mfma_f32_16x16x32_f16(qf0, kf[hh][0], z, 0, 0, 0);
        z = __builtin_amdgcn_mfma_f32_16x16x32_f16(qf1, kf[hh][1], z, 0, 0, 0);
        s[hh] = z;
      }
      bool diag = (kb + 63 > wq0);
#pragma unroll
      for (int r = 0; r < 4; r++) {
        int q = wq0 + quad * 4 + r;
        float p[4];
#pragma unroll
        for (int hh = 0; hh < 4; hh++) {
          float sc = s[hh][r];
          if (diag && (kb + 4 * col + hh > q)) sc = -1e30f;
          p[hh] = __builtin_exp2f(sc);
        }
        lsum[r] += (p[0] + p[1]) + (p[2] + p[3]);
        vhalf4 ph;
        ph[0] = (_Float16)p[0]; ph[1] = (_Float16)p[1];
        ph[2] = (_Float16)p[2]; ph[3] = (_Float16)p[3];
        *(vhalf4*)&Ps[wave][quad * 4 + r][4 * col] = ph;
      }
      // P write->read is wave-local; LDS drain only, no block barrier
      __asm__ __volatile__("s_waitcnt lgkmcnt(0)" ::: "memory");
      vhalf8 pf0 = *(const vhalf8*)&Ps[wave][col][quad * 8];
      vhalf8 pf1 = *(const vhalf8*)&Ps[wave][col][32 + quad * 8];
#pragma unroll
      for (int tt = 0; tt < 4; tt++) {
        vhalf8 vf0 = *(const vhalf8*)&Vs[tt * 16 + col][quad * 8];
        vhalf8 vf1 = *(const vhalf8*)&Vs[tt * 16 + col][32 + quad * 8];
        o[tt] = __builtin_amdgcn_mfma_f32_16x16x32_f16(pf0, vf0, o[tt], 0, 0, 0);
        o[tt] = __builtin_amdgcn_mfma_f32_16x16x32_f16(pf1, vf1, o[tt], 0, 0, 0);
      }
      __syncthreads();
    }

    // epilogue for this phase's 16 rows per wave
    float inv_l[4];
#pragma unroll
    for (int r = 0; r < 4; r++) {
      float rs = lsum[r];
#pragma unroll
      for (int msk = 1; msk < 16; msk <<= 1) rs += __shfl_xor(rs, msk, 64);
      inv_l[r] = 1.0f / rs;
    }
#pragma unroll
    for (int tt = 0; tt < 4; tt++)
#pragma unroll
      for (int r = 0; r < 4; r++) {
        int q = wq0 + quad * 4 + r;
        int d = tt * 16 + col;
        Vec[(size_t)(b * SEQ + q) * D_MODEL + h * HD + d] =
            (_Float16)(o[tt][r] * inv_l[r]);
      }
  }
}

// ---------------------------------------------------------------------------
extern "C" void kernel_launch(void* const* d_in, const int* in_sizes, int n_in,
                              void* d_out, int out_size, void* d_ws, size_t ws_size,
                              hipStream_t stream) {
  const float* x  = (const float*)d_in[0];
  const float* Wq = (const float*)d_in[1];
  const float* Wk = (const float*)d_in[2];
  const float* Wv = (const float*)d_in[3];
  const float* Wo = (const float*)d_in[4];
  float* out = (float*)d_out;

  char* ws = (char*)d_ws;
  _Float16* Xh     = (_Float16*)ws;                    // [4096][1024]   8 MiB
  _Float16* Wt_qkv = (_Float16*)(ws + 8388608);        // [3072][1024]   6 MiB
  _Float16* Wot    = (_Float16*)(ws + 14680064);       // [1024][1024]   2 MiB
  _Float16* QKV    = (_Float16*)(ws + 16777216);       // [4096][3072]  24 MiB (V region unused)
  _Float16* Vt     = (_Float16*)(ws + 41943040);       // [32][64][2048] 8 MiB
  _Float16* Vec    = (_Float16*)(ws + 50331648);       // [4096][1024]   8 MiB

  dim3 tb(256);
  prep<<<dim3(16, 16, 5), tb, 0, stream>>>(x, Wq, Wk, Wv, Wo, Xh, Wt_qkv, Wot);
  gemm128<128><<<dim3(32, 24), tb, 0, stream>>>(Xh, Wt_qkv, QKV, nullptr, Vt,
                                                4096, 3072, 1024, 2);
  attn<<<dim3(512), tb, 0, stream>>>(QKV, Vt, Vec);
  gemm128<64><<<dim3(32, 16), tb, 0, stream>>>(Vec, Wot, nullptr, out, nullptr,
                                               4096, 1024, 1024, 1);
}

// Round 11
// 183.980 us; speedup vs baseline: 1.2400x; 1.0473x over previous
//
#include <hip/hip_runtime.h>
#include <hip/hip_bf16.h>

// fp32 I/O, fp16 MFMA compute (verified: absmax 3.9e-3 vs thr 3.1e-2).
// R11: in-block split-K attention — 8-wave blocks, 2 halves process alternate
//      key tiles of one 64-row q-tile (fixed-offset softmax partials are
//      additive), LDS merge. Uniform 17 iters/block, 16 waves/CU.
//      QKV vmode epilogue packs 4 transposed stores into one 8B store.

typedef __attribute__((ext_vector_type(8))) _Float16 vhalf8;
typedef __attribute__((ext_vector_type(4))) _Float16 vhalf4;
typedef __attribute__((ext_vector_type(4))) float vfloat4;

#define D_MODEL 1024
#define SEQ     2048
#define NB      2
#define NH      16
#define HD      64

// softmax: exp(s/8) = exp2(s * 0.125*log2(e)); constant offset cancels in o/l.
#define SCALE_K1 0.18033688f

__device__ __forceinline__ void async16(const void* g, void* l) {
  __builtin_amdgcn_global_load_lds(
      (const __attribute__((address_space(1))) unsigned int*)g,
      (__attribute__((address_space(3))) unsigned int*)l, 16, 0, 0);
}

// ---------------------------------------------------------------------------
// prep: z<4 -> weight transpose+convert planes; z==4 -> x fp32->fp16 convert.
// ---------------------------------------------------------------------------
__global__ __launch_bounds__(256) void prep(
    const float* __restrict__ x,
    const float* __restrict__ Wq, const float* __restrict__ Wk,
    const float* __restrict__ Wv, const float* __restrict__ Wo,
    _Float16* __restrict__ Xh, _Float16* __restrict__ Wt_qkv,
    _Float16* __restrict__ Wot) {
  int z = blockIdx.z;
  int t = threadIdx.x;
  if (z == 4) {
    int id = blockIdx.y * 16 + blockIdx.x;
#pragma unroll
    for (int pass = 0; pass < 8; pass++) {
      size_t i = ((size_t)(pass * 256 + id) * 256 + t) * 8;
      float4 a = *(const float4*)&x[i];
      float4 b = *(const float4*)&x[i + 4];
      vhalf8 h;
      h[0] = (_Float16)a.x; h[1] = (_Float16)a.y;
      h[2] = (_Float16)a.z; h[3] = (_Float16)a.w;
      h[4] = (_Float16)b.x; h[5] = (_Float16)b.y;
      h[6] = (_Float16)b.z; h[7] = (_Float16)b.w;
      *(vhalf8*)&Xh[i] = h;
    }
    return;
  }
  __shared__ _Float16 tile[64][65];
  const float* in = (z == 0) ? Wq : (z == 1) ? Wk : (z == 2) ? Wv : Wo;
  _Float16* out = (z < 3) ? (Wt_qkv + (size_t)z * 1024 * 1024) : Wot;
  int c0 = blockIdx.x * 64, r0 = blockIdx.y * 64;
  int tc = t & 63, tr = t >> 6;
#pragma unroll
  for (int p = 0; p < 16; p++) {
    int r = tr + p * 4;
    tile[r][tc] = (_Float16)in[(size_t)(r0 + r) * 1024 + c0 + tc];
  }
  __syncthreads();
#pragma unroll
  for (int p = 0; p < 16; p++) {
    int r = tr + p * 4;
    out[(size_t)(c0 + r) * 1024 + r0 + tc] = tile[tc][r];
  }
}

// ---------------------------------------------------------------------------
// m97-style f16 GEMM: C[M][N] = A[M][K] @ Bt[N][K]^T.
// 128xBN tile, 4 waves, BK=32, global_load_lds width-16, XOR slot swizzle.
// mode 0: f16 out.  mode 1: f32 out.  mode 2 (QKV): f16 out, V cols
// (n >= 2048) written transposed into Vt[(b,h)][d][s] (packed 8B stores).
// ---------------------------------------------------------------------------
template <int BN>
__global__ __launch_bounds__(256) void gemm128(
    const _Float16* __restrict__ A, const _Float16* __restrict__ Bt,
    _Float16* __restrict__ Ch, float* __restrict__ Cf,
    _Float16* __restrict__ Vt, int M, int N, int K, int mode) {
  constexpr int ACH = 8;
  constexpr int BCH = BN / 16;
  constexpr int CPW = (ACH + BCH) / 4;
  constexpr int JN = BN / 32;
  __shared__ _Float16 As[128 * 32];
  __shared__ _Float16 Bs[BN * 32];
  int m0 = blockIdx.x * 128, n0 = blockIdx.y * BN;
  int t = threadIdx.x;
  int lane = t & 63, wave = t >> 6;
  int wm = (wave >> 1) * 64, wn = (wave & 1) * (BN / 2);
  int col = lane & 15, quad = lane >> 4;
  int srow = lane >> 2;
  int gcol = (((lane & 3) ^ (srow & 3)) << 3);

  vfloat4 acc[4][JN];
#pragma unroll
  for (int i = 0; i < 4; i++)
#pragma unroll
    for (int j = 0; j < JN; j++) {
      acc[i][j][0] = 0.f; acc[i][j][1] = 0.f;
      acc[i][j][2] = 0.f; acc[i][j][3] = 0.f;
    }

  int xq = (quad ^ (col & 3)) * 8;

  for (int k0 = 0; k0 < K; k0 += 32) {
    __syncthreads();
#pragma unroll
    for (int j = 0; j < CPW; j++) {
      int c = wave * CPW + j;
      if (c < ACH) {
        int row = c * 16 + srow;
        async16(&A[(size_t)(m0 + row) * K + k0 + gcol], &As[c * 512]);
      } else {
        int row = (c - ACH) * 16 + srow;
        async16(&Bt[(size_t)(n0 + row) * K + k0 + gcol], &Bs[(c - ACH) * 512]);
      }
    }
    __syncthreads();

    vhalf8 af[4], bf[JN];
#pragma unroll
    for (int i = 0; i < 4; i++)
      af[i] = *(const vhalf8*)&As[(wm + i * 16 + col) * 32 + xq];
#pragma unroll
    for (int j = 0; j < JN; j++)
      bf[j] = *(const vhalf8*)&Bs[(wn + j * 16 + col) * 32 + xq];
#pragma unroll
    for (int i = 0; i < 4; i++)
#pragma unroll
      for (int j = 0; j < JN; j++)
        acc[i][j] = __builtin_amdgcn_mfma_f32_16x16x32_f16(af[i], bf[j], acc[i][j], 0, 0, 0);
  }

  bool vmode = (mode == 2) && (n0 >= 2048);
#pragma unroll
  for (int i = 0; i < 4; i++)
#pragma unroll
    for (int j = 0; j < JN; j++) {
      if (vmode) {
        // transposed V write: r=0..3 are consecutive ss -> one 8B store
        int n = n0 + wn + j * 16 + col;
        int nn = n - 2048;
        int hh = nn >> 6, dd = nn & 63;
        int m_base = m0 + wm + i * 16 + quad * 4;
        int bb = m_base >> 11, ss = m_base & 2047;
        vhalf4 pk;
        pk[0] = (_Float16)acc[i][j][0]; pk[1] = (_Float16)acc[i][j][1];
        pk[2] = (_Float16)acc[i][j][2]; pk[3] = (_Float16)acc[i][j][3];
        *(vhalf4*)&Vt[(((size_t)bb * NH + hh) * HD + dd) * SEQ + ss] = pk;
      } else {
#pragma unroll
        for (int r = 0; r < 4; r++) {
          int m = m0 + wm + i * 16 + quad * 4 + r;
          int n = n0 + wn + j * 16 + col;
          if (mode == 1)
            Cf[(size_t)m * N + n] = acc[i][j][r];
          else
            Ch[(size_t)m * N + n] = (_Float16)acc[i][j][r];
        }
      }
    }
}

// ---------------------------------------------------------------------------
// Flash attention, causal, fixed-offset softmax, IN-BLOCK SPLIT-K.
// 8 waves (512 thr)/block: half hf = wave>>2 processes alternate 64-key
// tiles (own Ks/Vs buffer); sub-wave sw = wave&3 owns 16 q-rows. Partial
// (o, l) merged through LDS (exact: fixed offset is order-independent).
// Two phases per block: q-tiles {31-pp, pp} -> exactly 17 iters for all
// blocks. Grid 512 = 2 blocks/CU = 16 waves/CU.
// ---------------------------------------------------------------------------
__global__ __launch_bounds__(512) void attn(
    const _Float16* __restrict__ QKV, const _Float16* __restrict__ Vt,
    _Float16* __restrict__ Vec) {
  int blk = blockIdx.x;
  int pp = blk >> 5;            // 0..15
  int hb = blk & 31;
  int h = hb & 15;
  int b = hb >> 4;

  const _Float16* Qb  = QKV + (size_t)(b * SEQ) * 3072 + h * HD;
  const _Float16* Kb  = QKV + (size_t)(b * SEQ) * 3072 + 1024 + h * HD;
  const _Float16* Vtb = Vt + (size_t)(b * NH + h) * HD * SEQ;

  int t = threadIdx.x;
  int lane = t & 63, wave = t >> 6;
  int sw = wave & 3, hf = wave >> 2;
  int col = lane & 15, quad = lane >> 4;

  __shared__ _Float16 Ks[2][64][72];
  __shared__ _Float16 Vs[2][64][72];
  __shared__ _Float16 Ps[8][16][72];
  __shared__ float Om[64][65];
  __shared__ float Lm[64];

  // staging: 256 threads per half, one K-vhalf8-pair + V-pair each
  int tl = t & 255;
  int srow = tl >> 2;
  int scol = (tl & 3) * 16;
  int kslot = ((srow & 3) << 4) + (srow >> 2);   // K row permutation
  int kcol = scol ^ ((srow & 3) << 4);           // XOR bank swizzle

  int tiles[2] = {31 - pp, pp};

  // prologue: prefetch this half's first tile of phase 0 (ti = hf)
  vhalf8 kr0, kr1, vr0, vr1;
  {
    const _Float16* kg = &Kb[(size_t)(hf * 64 + srow) * 3072 + scol];
    kr0 = *(const vhalf8*)kg; kr1 = *(const vhalf8*)(kg + 8);
    const _Float16* vg = &Vtb[(size_t)srow * SEQ + hf * 64 + scol];
    vr0 = *(const vhalf8*)vg; vr1 = *(const vhalf8*)(vg + 8);
  }

#pragma unroll
  for (int phase = 0; phase < 2; phase++) {
    int qt = tiles[phase];
    int q0 = qt * 64;
    int ntk = qt + 1;            // key tiles for this q-tile
    int J = (ntk + 1) >> 1;      // block-uniform loop count
    int wq0 = q0 + sw * 16;

    // Q fragments, pre-scaled so softmax is bare exp2(s)
    vhalf8 qf0 = *(const vhalf8*)&Qb[(size_t)(wq0 + col) * 3072 + quad * 8];
    vhalf8 qf1 = *(const vhalf8*)&Qb[(size_t)(wq0 + col) * 3072 + 32 + quad * 8];
#pragma unroll
    for (int i = 0; i < 8; i++) {
      qf0[i] = qf0[i] * (_Float16)SCALE_K1;
      qf1[i] = qf1[i] * (_Float16)SCALE_K1;
    }

    vfloat4 o[4];
#pragma unroll
    for (int i = 0; i < 4; i++) { o[i][0]=0.f; o[i][1]=0.f; o[i][2]=0.f; o[i][3]=0.f; }
    float lsum[4] = {0.f, 0.f, 0.f, 0.f};

    for (int j = 0; j < J; j++) {
      int ti = 2 * j + hf;
      bool active = (ti < ntk);
      int kb = ti * 64;
      if (active) {
        *(vhalf8*)&Ks[hf][kslot][kcol]     = kr0;
        *(vhalf8*)&Ks[hf][kslot][kcol + 8] = kr1;
        *(vhalf8*)&Vs[hf][srow][scol]      = vr0;
        *(vhalf8*)&Vs[hf][srow][scol + 8]  = vr1;
      }
      __syncthreads();

      // prefetch this half's next tile (phase-aware), overlaps compute
      {
        int tnext;
        if (phase == 0)
          tnext = (ti + 2 < ntk) ? (ti + 2) : hf;  // else: phase 1's first
        else
          tnext = (ti + 2 < ntk) ? (ti + 2) : ti;  // dead reload, harmless
        int kpf = tnext * 64;
        const _Float16* kg = &Kb[(size_t)(kpf + srow) * 3072 + scol];
        kr0 = *(const vhalf8*)kg; kr1 = *(const vhalf8*)(kg + 8);
        const _Float16* vg = &Vtb[(size_t)srow * SEQ + kpf + scol];
        vr0 = *(const vhalf8*)vg; vr1 = *(const vhalf8*)(vg + 8);
      }

      if (active) {
        // QK^T: 16 rows x 64 keys (K rows permuted: tile hh row c = key 4c+hh)
        vhalf8 kf[4][2];
#pragma unroll
        for (int hh = 0; hh < 4; hh++) {
          int swz = hh << 4;
          kf[hh][0] = *(const vhalf8*)&Ks[hf][hh * 16 + col][(quad * 8) ^ swz];
          kf[hh][1] = *(const vhalf8*)&Ks[hf][hh * 16 + col][(32 + quad * 8) ^ swz];
        }
        vfloat4 s[4];
#pragma unroll
        for (int hh = 0; hh < 4; hh++) {
          vfloat4 z; z[0]=0.f; z[1]=0.f; z[2]=0.f; z[3]=0.f;
          z = __builtin_amdgcn_mfma_f32_16x16x32_f16(qf0, kf[hh][0], z, 0, 0, 0);
          z = __builtin_amdgcn_mfma_f32_16x16x32_f16(qf1, kf[hh][1], z, 0, 0, 0);
          s[hh] = z;
        }
        bool diag = (kb + 63 > wq0);
#pragma unroll
        for (int r = 0; r < 4; r++) {
          int q = wq0 + quad * 4 + r;
          float p[4];
#pragma unroll
          for (int hh = 0; hh < 4; hh++) {
            float sc = s[hh][r];
            if (diag && (kb + 4 * col + hh > q)) sc = -1e30f;
            p[hh] = __builtin_exp2f(sc);
          }
          lsum[r] += (p[0] + p[1]) + (p[2] + p[3]);
          vhalf4 ph;
          ph[0] = (_Float16)p[0]; ph[1] = (_Float16)p[1];
          ph[2] = (_Float16)p[2]; ph[3] = (_Float16)p[3];
          *(vhalf4*)&Ps[wave][quad * 4 + r][4 * col] = ph;
        }
        // P write->read is wave-local; LDS drain only
        __asm__ __volatile__("s_waitcnt lgkmcnt(0)" ::: "memory");
        vhalf8 pf0 = *(const vhalf8*)&Ps[wave][col][quad * 8];
        vhalf8 pf1 = *(const vhalf8*)&Ps[wave][col][32 + quad * 8];
#pragma unroll
        for (int tt = 0; tt < 4; tt++) {
          vhalf8 vf0 = *(const vhalf8*)&Vs[hf][tt * 16 + col][quad * 8];
          vhalf8 vf1 = *(const vhalf8*)&Vs[hf][tt * 16 + col][32 + quad * 8];
          o[tt] = __builtin_amdgcn_mfma_f32_16x16x32_f16(pf0, vf0, o[tt], 0, 0, 0);
          o[tt] = __builtin_amdgcn_mfma_f32_16x16x32_f16(pf1, vf1, o[tt], 0, 0, 0);
        }
      }
      __syncthreads();
    }

    // merge halves: half 1 -> LDS, half 0 adds + normalizes + writes
    float rs[4];
#pragma unroll
    for (int r = 0; r < 4; r++) {
      float v = lsum[r];
#pragma unroll
      for (int msk = 1; msk < 16; msk <<= 1) v += __shfl_xor(v, msk, 64);
      rs[r] = v;
    }
    if (hf == 1) {
#pragma unroll
      for (int tt = 0; tt < 4; tt++)
#pragma unroll
        for (int r = 0; r < 4; r++)
          Om[sw * 16 + quad * 4 + r][tt * 16 + col] = o[tt][r];
      if (col == 0)
#pragma unroll
        for (int r = 0; r < 4; r++)
          Lm[sw * 16 + quad * 4 + r] = rs[r];
    }
    __syncthreads();
    if (hf == 0) {
      float inv_l[4];
#pragma unroll
      for (int r = 0; r < 4; r++)
        inv_l[r] = 1.0f / (rs[r] + Lm[sw * 16 + quad * 4 + r]);
#pragma unroll
      for (int tt = 0; tt < 4; tt++)
#pragma unroll
        for (int r = 0; r < 4; r++) {
          int q = wq0 + quad * 4 + r;
          int d = tt * 16 + col;
          float ov = o[tt][r] + Om[sw * 16 + quad * 4 + r][tt * 16 + col];
          Vec[(size_t)(b * SEQ + q) * D_MODEL + h * HD + d] =
              (_Float16)(ov * inv_l[r]);
        }
    }
  }
}

// ---------------------------------------------------------------------------
extern "C" void kernel_launch(void* const* d_in, const int* in_sizes, int n_in,
                              void* d_out, int out_size, void* d_ws, size_t ws_size,
                              hipStream_t stream) {
  const float* x  = (const float*)d_in[0];
  const float* Wq = (const float*)d_in[1];
  const float* Wk = (const float*)d_in[2];
  const float* Wv = (const float*)d_in[3];
  const float* Wo = (const float*)d_in[4];
  float* out = (float*)d_out;

  char* ws = (char*)d_ws;
  _Float16* Xh     = (_Float16*)ws;                    // [4096][1024]   8 MiB
  _Float16* Wt_qkv = (_Float16*)(ws + 8388608);        // [3072][1024]   6 MiB
  _Float16* Wot    = (_Float16*)(ws + 14680064);       // [1024][1024]   2 MiB
  _Float16* QKV    = (_Float16*)(ws + 16777216);       // [4096][3072]  24 MiB (V region unused)
  _Float16* Vt     = (_Float16*)(ws + 41943040);       // [32][64][2048] 8 MiB
  _Float16* Vec    = (_Float16*)(ws + 50331648);       // [4096][1024]   8 MiB

  dim3 tb(256);
  prep<<<dim3(16, 16, 5), tb, 0, stream>>>(x, Wq, Wk, Wv, Wo, Xh, Wt_qkv, Wot);
  gemm128<128><<<dim3(32, 24), tb, 0, stream>>>(Xh, Wt_qkv, QKV, nullptr, Vt,
                                                4096, 3072, 1024, 2);
  attn<<<dim3(512), dim3(512), 0, stream>>>(QKV, Vt, Vec);
  gemm128<64><<<dim3(32, 16), tb, 0, stream>>>(Vec, Wot, nullptr, out, nullptr,
                                               4096, 1024, 1024, 1);
}